// Round 9
// baseline (170.705 us; speedup 1.0000x reference)
//
#include <hip/hip_runtime.h>
#include <hip/hip_bf16.h>

typedef __attribute__((ext_vector_type(8))) short bf16x8;
typedef __attribute__((ext_vector_type(4))) float f32x4;
typedef __attribute__((ext_vector_type(16))) float f32x16;

#define DEV static __device__ __forceinline__

constexpr int Cc = 256;
constexpr int Ll = 2304;
constexpr float SM_C = 0.25503486f;  // log2(e)/sqrt(32), folded into WQ/BQ

#if __has_builtin(__builtin_amdgcn_exp2f)
#define EXP2(x) __builtin_amdgcn_exp2f(x)
#else
#define EXP2(x) exp2f(x)
#endif
#if __has_builtin(__builtin_amdgcn_rcpf)
#define RCP(x) __builtin_amdgcn_rcpf(x)
#else
#define RCP(x) (1.0f / (x))
#endif

DEV unsigned short f2bf(float f) {
  union { float f; unsigned u; } v; v.f = f;
  unsigned r = v.u + 0x7FFFu + ((v.u >> 16) & 1u);
  return (unsigned short)(r >> 16);
}

DEV unsigned short f2bfc(float f) {
  union { __hip_bfloat16 h; unsigned short u; } c;
  c.h = __float2bfloat16(f);
  return c.u;
}

DEV unsigned packbf(float lo, float hi) {  // compiler fuses to cvt_pk
  return (unsigned)f2bfc(lo) | ((unsigned)f2bfc(hi) << 16);
}

// Convert weights fp32 -> bf16 (wq scaled by SM_C). wb layout [m][256][256].
__global__ __launch_bounds__(256) void k_wconv(
    const float* __restrict__ wq, const float* __restrict__ wk,
    const float* __restrict__ wv, const float* __restrict__ wo,
    unsigned short* __restrict__ wb) {
  int m = blockIdx.y;
  const float* src = (m == 0) ? wq : (m == 1) ? wk : (m == 2) ? wv : wo;
  float sc = (m == 0) ? SM_C : 1.0f;
  int i = (blockIdx.x * 256 + threadIdx.x) * 8;
  float4 f0 = *(const float4*)&src[i];
  float4 f1 = *(const float4*)&src[i + 4];
  uint4 o;
  o.x = (unsigned)f2bf(f0.x * sc) | ((unsigned)f2bf(f0.y * sc) << 16);
  o.y = (unsigned)f2bf(f0.z * sc) | ((unsigned)f2bf(f0.w * sc) << 16);
  o.z = (unsigned)f2bf(f1.x * sc) | ((unsigned)f2bf(f1.y * sc) << 16);
  o.w = (unsigned)f2bf(f1.z * sc) | ((unsigned)f2bf(f1.w * sc) << 16);
  *(uint4*)&wb[(size_t)m * 65536 + i] = o;
}

// X[b][c][l] fp32 -> XT[b][l][c] bf16
__global__ __launch_bounds__(256) void k_xpose(const float* __restrict__ x,
                                               unsigned short* __restrict__ xt) {
  int b = blockIdx.z;
  int c0 = blockIdx.y * 32;
  int l = blockIdx.x * 256 + threadIdx.x;
  const float* xp = x + (size_t)b * Cc * Ll + l;
  unsigned short* op = xt + ((size_t)b * Ll + l) * Cc + c0;
  float v[32];
#pragma unroll
  for (int j = 0; j < 32; ++j) v[j] = xp[(size_t)(c0 + j) * Ll];
  unsigned u[16];
#pragma unroll
  for (int j = 0; j < 16; ++j)
    u[j] = (unsigned)f2bf(v[2 * j]) | ((unsigned)f2bf(v[2 * j + 1]) << 16);
  uint4* o4 = (uint4*)op;
#pragma unroll
  for (int j = 0; j < 4; ++j)
    o4[j] = make_uint4(u[4 * j], u[4 * j + 1], u[4 * j + 2], u[4 * j + 3]);
}

// Merged QKV projection: stage X-tile once, run all 3 weight matrices.
// Outputs: QT/KT [b][h][l][d] bf16 (Q pre-scaled); Vp [b][h][d][kl'] bf16 where
// kl' applies the within-16 quad-swap pi (so attention's PV B-operand loads are
// contiguous 16B in the sigma order).
__global__ __launch_bounds__(256) void k_qkv(
    const unsigned short* __restrict__ xt, const unsigned short* __restrict__ wb,
    const float* __restrict__ bq, const float* __restrict__ bk,
    const float* __restrict__ bv,
    unsigned short* __restrict__ qt, unsigned short* __restrict__ kt,
    unsigned short* __restrict__ vm) {
  __shared__ __align__(16) unsigned short Bs[64][264];
  int b = blockIdx.z;
  int m0 = blockIdx.y * 64, n0 = blockIdx.x * 64;
  int tid = threadIdx.x, lane = tid & 63, wave = tid >> 6;
  int g = lane >> 4, cl = lane & 15;
  const uint4* bp = (const uint4*)(xt + ((size_t)b * Ll + n0) * 256);
#pragma unroll
  for (int j = 0; j < 8; ++j) {
    int idx = j * 256 + tid;
    *(uint4*)&Bs[idx >> 5][(idx & 31) * 8] = bp[idx];
  }
  __syncthreads();
  int ob = m0 + wave * 16 + g * 4;
  int h = ob >> 5, d0 = ob & 31;
#pragma unroll
  for (int p = 0; p < 3; ++p) {
    const unsigned short* Wrow =
        wb + (size_t)p * 65536 + (size_t)(m0 + wave * 16 + cl) * 256 + g * 8;
    bf16x8 af[8];
#pragma unroll
    for (int ks = 0; ks < 8; ++ks) af[ks] = *(const bf16x8*)&Wrow[ks * 32];
    f32x4 acc[4] = {};
#pragma unroll
    for (int ks = 0; ks < 8; ++ks) {
#pragma unroll
      for (int nf = 0; nf < 4; ++nf) {
        bf16x8 bb = *(const bf16x8*)&Bs[nf * 16 + cl][ks * 32 + g * 8];
        acc[nf] = __builtin_amdgcn_mfma_f32_16x16x32_bf16(af[ks], bb, acc[nf], 0, 0, 0);
      }
    }
    const float* bias = (p == 0) ? bq : (p == 1) ? bk : bv;
    float sc = (p == 0) ? SM_C : 1.0f;
    float b0 = bias[ob] * sc, b1 = bias[ob + 1] * sc;
    float b2 = bias[ob + 2] * sc, b3 = bias[ob + 3] * sc;
#pragma unroll
    for (int nf = 0; nf < 4; ++nf) {
      int l = n0 + nf * 16 + cl;
      float v0 = acc[nf][0] + b0, v1 = acc[nf][1] + b1;
      float v2 = acc[nf][2] + b2, v3 = acc[nf][3] + b3;
      if (p < 2) {
        unsigned short* dst = ((p == 0) ? qt : kt) +
            ((size_t)(b * 8 + h) * Ll + l) * 32 + d0;
        *(uint2*)dst = make_uint2(packbf(v0, v1), packbf(v2, v3));
      } else {
        // pi: swap quads 1<->2 within each 16 (bits b2<->b3 of cl) — involution
        int lp = n0 + nf * 16 + ((cl & 3) | ((cl & 4) << 1) | ((cl & 8) >> 1));
        size_t base = (size_t)(b * 8 + h) * 32 + d0;
        vm[(base + 0) * Ll + lp] = f2bfc(v0);
        vm[(base + 1) * Ll + lp] = f2bfc(v1);
        vm[(base + 2) * Ll + lp] = f2bfc(v2);
        vm[(base + 3) * Ll + lp] = f2bfc(v3);
      }
    }
  }
}

// One tile-step of the LDS-free flash attention: QK^T (swapped), exp2,
// pack-to-bf16 in natural register order, PV + ones-MFMA denominator with
// sigma-matched V (loaded from the pi-permuted Vp layout).
DEV void attn_step(uint4 k0, uint4 k1, uint4 k2, uint4 k3,
                   uint4 v0, uint4 v1, uint4 v2, uint4 v3,
                   bf16x8 qf0, bf16x8 qf1, bf16x8 ones,
                   f32x16& oacc, f32x16& osum) {
  union U { uint4 u; bf16x8 v; };
  U a0{k0}, a1{k1}, a2{k2}, a3{k3}, w0{v0}, w1{v1}, w2{v2}, w3{v3};
  f32x16 p0 = {}, p1 = {};
  p0 = __builtin_amdgcn_mfma_f32_32x32x16_bf16(a0.v, qf0, p0, 0, 0, 0);
  p0 = __builtin_amdgcn_mfma_f32_32x32x16_bf16(a1.v, qf1, p0, 0, 0, 0);
  p1 = __builtin_amdgcn_mfma_f32_32x32x16_bf16(a2.v, qf0, p1, 0, 0, 0);
  p1 = __builtin_amdgcn_mfma_f32_32x32x16_bf16(a3.v, qf1, p1, 0, 0, 0);
#pragma unroll
  for (int r = 0; r < 16; ++r) { p0[r] = EXP2(p0[r]); p1[r] = EXP2(p1[r]); }
  union { unsigned w[16]; bf16x8 v8[4]; } Wp;
#pragma unroll
  for (int m = 0; m < 8; ++m) {
    Wp.w[m] = packbf(p0[2 * m], p0[2 * m + 1]);
    Wp.w[8 + m] = packbf(p1[2 * m], p1[2 * m + 1]);
  }
  oacc = __builtin_amdgcn_mfma_f32_32x32x16_bf16(Wp.v8[0], w0.v, oacc, 0, 0, 0);
  osum = __builtin_amdgcn_mfma_f32_32x32x16_bf16(Wp.v8[0], ones, osum, 0, 0, 0);
  oacc = __builtin_amdgcn_mfma_f32_32x32x16_bf16(Wp.v8[1], w1.v, oacc, 0, 0, 0);
  osum = __builtin_amdgcn_mfma_f32_32x32x16_bf16(Wp.v8[1], ones, osum, 0, 0, 0);
  oacc = __builtin_amdgcn_mfma_f32_32x32x16_bf16(Wp.v8[2], w2.v, oacc, 0, 0, 0);
  osum = __builtin_amdgcn_mfma_f32_32x32x16_bf16(Wp.v8[2], ones, osum, 0, 0, 0);
  oacc = __builtin_amdgcn_mfma_f32_32x32x16_bf16(Wp.v8[3], w3.v, oacc, 0, 0, 0);
  osum = __builtin_amdgcn_mfma_f32_32x32x16_bf16(Wp.v8[3], ones, osum, 0, 0, 0);
}

#define LDK(d0, d1, d2, d3, J)                              \
  d0 = *(const uint4*)(kl0 + ((J) * 64 + 0) * 32 + 0);      \
  d1 = *(const uint4*)(kl0 + ((J) * 64 + 0) * 32 + 16);     \
  d2 = *(const uint4*)(kl0 + ((J) * 64 + 32) * 32 + 0);     \
  d3 = *(const uint4*)(kl0 + ((J) * 64 + 32) * 32 + 16);
#define LDV(d0, d1, d2, d3, J)                  \
  d0 = *(const uint4*)(vl0 + (J) * 64 + 0);     \
  d1 = *(const uint4*)(vl0 + (J) * 64 + 16);    \
  d2 = *(const uint4*)(vl0 + (J) * 64 + 32);    \
  d3 = *(const uint4*)(vl0 + (J) * 64 + 48);

// Flash attention, LDS-free main loop + 2-way kl-stream split for occupancy:
// block = 4 waves = 2 q-subtiles x 2 kl-streams (18 tiles each), pair-combined
// in a small LDS epilogue (one barrier). K/V global->reg, L2-hot (bh = blk&31).
__global__ __launch_bounds__(256) void k_attn(
    const unsigned short* __restrict__ qt,
    const unsigned short* __restrict__ kt,
    const unsigned short* __restrict__ vp,
    unsigned short* __restrict__ aot) {
  __shared__ float Osh[2][32][33];
  __shared__ float Ssh[2][32];
  int n = blockIdx.x;
  int bh = n & 31, q64 = n >> 5;  // bh fastest => same-XCD blocks share bh
  int b = bh >> 3, h = bh & 7;
  int tid = threadIdx.x, wave = tid >> 6, lane = tid & 63;
  int qsub = wave >> 1, sstr = wave & 1;
  int hi = lane >> 5, c = lane & 31;

  const unsigned short* qb = qt + (size_t)bh * Ll * 32;
  const unsigned short* kl0 = kt + (size_t)bh * Ll * 32 +
      (size_t)(sstr * 18 * 64) * 32 + (size_t)c * 32 + hi * 8;
  const unsigned short* vl0 = vp + (size_t)bh * 32 * Ll + (size_t)c * Ll +
      sstr * 18 * 64 + hi * 8;

  int qrow0 = q64 * 64 + qsub * 32;
  bf16x8 qf0 = *(const bf16x8*)&qb[(size_t)(qrow0 + c) * 32 + hi * 8];
  bf16x8 qf1 = *(const bf16x8*)&qb[(size_t)(qrow0 + c) * 32 + 16 + hi * 8];

  bf16x8 ones;
#pragma unroll
  for (int i = 0; i < 8; ++i) ones[i] = (short)0x3F80;

  f32x16 oacc = {}, osum = {};

  uint4 ka0, ka1, ka2, ka3, kb0, kb1, kb2, kb3, va0, va1, va2, va3;
  LDK(ka0, ka1, ka2, ka3, 0);
  for (int j = 0; j < 18; j += 2) {
    LDV(va0, va1, va2, va3, j);          // needed after QK+exp2 (~300 cyc away)
    LDK(kb0, kb1, kb2, kb3, j + 1);      // prefetch next K tile
    attn_step(ka0, ka1, ka2, ka3, va0, va1, va2, va3, qf0, qf1, ones, oacc, osum);
    LDV(va0, va1, va2, va3, j + 1);
    if (j + 2 < 18) { LDK(ka0, ka1, ka2, ka3, j + 2); }
    attn_step(kb0, kb1, kb2, kb3, va0, va1, va2, va3, qf0, qf1, ones, oacc, osum);
  }

  // pair-combine the two kl-streams, normalize, store
  if (sstr == 1) {
#pragma unroll
    for (int r = 0; r < 16; ++r) {
      int qrl = (r & 3) + 8 * (r >> 2) + 4 * hi;
      Osh[qsub][qrl][c] = oacc[r];
      if (c == 0) Ssh[qsub][qrl] = osum[r];
    }
  }
  __syncthreads();
  if (sstr == 0) {
    unsigned short* ob = aot + ((size_t)b * Ll + qrow0) * 256 + h * 32 + c;
#pragma unroll
    for (int r = 0; r < 16; ++r) {
      int qrl = (r & 3) + 8 * (r >> 2) + 4 * hi;
      float ot = oacc[r] + Osh[qsub][qrl][c];
      float st = osum[r] + Ssh[qsub][qrl];
      ob[(size_t)qrl * 256] = f2bfc(ot * RCP(st));
    }
  }
}

// Final projection: out[b][o][l] fp32 = wo . AOT + bo
__global__ __launch_bounds__(256) void k_oproj(
    const unsigned short* __restrict__ aot, const unsigned short* __restrict__ wb,
    const float* __restrict__ bo, float* __restrict__ out) {
  __shared__ __align__(16) unsigned short Bs[64][264];
  int b = blockIdx.z;
  int m0 = blockIdx.y * 64, n0 = blockIdx.x * 64;
  int tid = threadIdx.x, lane = tid & 63, wave = tid >> 6;
  int g = lane >> 4, cl = lane & 15;
  const uint4* bp = (const uint4*)(aot + ((size_t)b * Ll + n0) * 256);
#pragma unroll
  for (int j = 0; j < 8; ++j) {
    int idx = j * 256 + tid;
    *(uint4*)&Bs[idx >> 5][(idx & 31) * 8] = bp[idx];
  }
  __syncthreads();
  const unsigned short* Wrow =
      wb + (size_t)3 * 65536 + (size_t)(m0 + wave * 16 + cl) * 256 + g * 8;
  bf16x8 af[8];
#pragma unroll
  for (int ks = 0; ks < 8; ++ks) af[ks] = *(const bf16x8*)&Wrow[ks * 32];
  f32x4 acc[4] = {};
#pragma unroll
  for (int ks = 0; ks < 8; ++ks) {
#pragma unroll
    for (int nf = 0; nf < 4; ++nf) {
      bf16x8 bb = *(const bf16x8*)&Bs[nf * 16 + cl][ks * 32 + g * 8];
      acc[nf] = __builtin_amdgcn_mfma_f32_16x16x32_bf16(af[ks], bb, acc[nf], 0, 0, 0);
    }
  }
  int ob = m0 + wave * 16 + g * 4;
  float b0 = bo[ob], b1 = bo[ob + 1], b2 = bo[ob + 2], b3 = bo[ob + 3];
#pragma unroll
  for (int nf = 0; nf < 4; ++nf) {
    int l = n0 + nf * 16 + cl;
    float* dst = out + ((size_t)b * 256 + ob) * Ll + l;
    dst[(size_t)0 * Ll] = acc[nf][0] + b0;
    dst[(size_t)1 * Ll] = acc[nf][1] + b1;
    dst[(size_t)2 * Ll] = acc[nf][2] + b2;
    dst[(size_t)3 * Ll] = acc[nf][3] + b3;
  }
}

extern "C" void kernel_launch(void* const* d_in, const int* in_sizes, int n_in,
                              void* d_out, int out_size, void* d_ws, size_t ws_size,
                              hipStream_t stream) {
  (void)in_sizes; (void)n_in; (void)out_size; (void)ws_size;
  const float* x  = (const float*)d_in[0];
  const float* wq = (const float*)d_in[1];
  const float* bq = (const float*)d_in[2];
  const float* wk = (const float*)d_in[3];
  const float* bk = (const float*)d_in[4];
  const float* wv = (const float*)d_in[5];
  const float* bv = (const float*)d_in[6];
  const float* wo = (const float*)d_in[7];
  const float* bo = (const float*)d_in[8];
  float* out = (float*)d_out;

  const size_t CH = (size_t)4 * Ll * Cc;  // elements per bf16 chunk
  unsigned short* xt = (unsigned short*)d_ws;
  unsigned short* qt = xt + CH;
  unsigned short* kt = xt + 2 * CH;
  unsigned short* vm = xt + 3 * CH;
  unsigned short* wbq = xt + 4 * CH;  // [4][256][256] bf16 weights
  unsigned short* aot = xt;           // reuse XT slot after projections

  k_wconv<<<dim3(32, 4), 256, 0, stream>>>(wq, wk, wv, wo, wbq);
  k_xpose<<<dim3(9, 8, 4), 256, 0, stream>>>(x, xt);
  k_qkv<<<dim3(36, 4, 4), 256, 0, stream>>>(xt, wbq, bq, bk, bv, qt, kt, vm);
  k_attn<<<dim3(1152), 256, 0, stream>>>(qt, kt, vm, aot);
  k_oproj<<<dim3(36, 4, 4), 256, 0, stream>>>(aot, wbq, bo, out);
}

// Round 11
// 151.480 us; speedup vs baseline: 1.1269x; 1.1269x over previous
//
#include <hip/hip_runtime.h>
#include <hip/hip_bf16.h>

typedef __attribute__((ext_vector_type(8))) short bf16x8;
typedef __attribute__((ext_vector_type(4))) float f32x4;
typedef __attribute__((ext_vector_type(16))) float f32x16;

#define DEV static __device__ __forceinline__

constexpr int Cc = 256;
constexpr int Ll = 2304;
constexpr float SM_C = 0.25503486f;  // log2(e)/sqrt(32), folded into WQ/BQ

#if __has_builtin(__builtin_amdgcn_exp2f)
#define EXP2(x) __builtin_amdgcn_exp2f(x)
#else
#define EXP2(x) exp2f(x)
#endif
#if __has_builtin(__builtin_amdgcn_rcpf)
#define RCP(x) __builtin_amdgcn_rcpf(x)
#else
#define RCP(x) (1.0f / (x))
#endif

DEV unsigned short f2bf(float f) {
  union { float f; unsigned u; } v; v.f = f;
  unsigned r = v.u + 0x7FFFu + ((v.u >> 16) & 1u);
  return (unsigned short)(r >> 16);
}

DEV unsigned short f2bfc(float f) {
  union { __hip_bfloat16 h; unsigned short u; } c;
  c.h = __float2bfloat16(f);
  return c.u;
}

// RNE pack via compiler path. NOTE (round 10 post-mortem): inline-asm
// v_cvt_pk_bf16_f32 here broke correctness (absmax 0.0039 -> 0.039; rounding
// mode != RNE). Keep the compiler conversion.
DEV unsigned packbf(float lo, float hi) {
  return (unsigned)f2bfc(lo) | ((unsigned)f2bfc(hi) << 16);
}

// Merged prep: blocks 0..127 convert weights fp32->bf16 (wq scaled by SM_C)
// into wb [m][256][256]; blocks 128..415 transpose X[b][c][l] -> XT[b][l][c].
__global__ __launch_bounds__(256) void k_prep(
    const float* __restrict__ x,
    const float* __restrict__ wq, const float* __restrict__ wk,
    const float* __restrict__ wv, const float* __restrict__ wo,
    unsigned short* __restrict__ wb, unsigned short* __restrict__ xt) {
  int bid = blockIdx.x;
  if (bid < 128) {
    int m = bid >> 5;
    const float* src = (m == 0) ? wq : (m == 1) ? wk : (m == 2) ? wv : wo;
    float sc = (m == 0) ? SM_C : 1.0f;
    int i = ((bid & 31) * 256 + threadIdx.x) * 8;
    float4 f0 = *(const float4*)&src[i];
    float4 f1 = *(const float4*)&src[i + 4];
    uint4 o;
    o.x = (unsigned)f2bf(f0.x * sc) | ((unsigned)f2bf(f0.y * sc) << 16);
    o.y = (unsigned)f2bf(f0.z * sc) | ((unsigned)f2bf(f0.w * sc) << 16);
    o.z = (unsigned)f2bf(f1.x * sc) | ((unsigned)f2bf(f1.y * sc) << 16);
    o.w = (unsigned)f2bf(f1.z * sc) | ((unsigned)f2bf(f1.w * sc) << 16);
    *(uint4*)&wb[(size_t)m * 65536 + i] = o;
  } else {
    int t = bid - 128;  // 288 blocks: b(4) x c0(8) x lblk(9)
    int b = t / 72, rem = t % 72;
    int c0 = (rem / 9) * 32, lblk = rem % 9;
    int l = lblk * 256 + threadIdx.x;
    const float* xp = x + (size_t)b * Cc * Ll + l;
    unsigned short* op = xt + ((size_t)b * Ll + l) * Cc + c0;
    float v[32];
#pragma unroll
    for (int j = 0; j < 32; ++j) v[j] = xp[(size_t)(c0 + j) * Ll];
    unsigned u[16];
#pragma unroll
    for (int j = 0; j < 16; ++j)
      u[j] = (unsigned)f2bf(v[2 * j]) | ((unsigned)f2bf(v[2 * j + 1]) << 16);
    uint4* o4 = (uint4*)op;
#pragma unroll
    for (int j = 0; j < 4; ++j)
      o4[j] = make_uint4(u[4 * j], u[4 * j + 1], u[4 * j + 2], u[4 * j + 3]);
  }
}

// Merged QKV projection: stage X-tile once, run all 3 weight matrices.
// Outputs: QT/KT [b][h][l][d] bf16 (Q pre-scaled); V [b][h][d][l] bf16.
__global__ __launch_bounds__(256) void k_qkv(
    const unsigned short* __restrict__ xt, const unsigned short* __restrict__ wb,
    const float* __restrict__ bq, const float* __restrict__ bk,
    const float* __restrict__ bv,
    unsigned short* __restrict__ qt, unsigned short* __restrict__ kt,
    unsigned short* __restrict__ vm) {
  __shared__ __align__(16) unsigned short Bs[64][264];
  int b = blockIdx.z;
  int m0 = blockIdx.y * 64, n0 = blockIdx.x * 64;
  int tid = threadIdx.x, lane = tid & 63, wave = tid >> 6;
  int g = lane >> 4, cl = lane & 15;
  const uint4* bp = (const uint4*)(xt + ((size_t)b * Ll + n0) * 256);
#pragma unroll
  for (int j = 0; j < 8; ++j) {
    int idx = j * 256 + tid;
    *(uint4*)&Bs[idx >> 5][(idx & 31) * 8] = bp[idx];
  }
  __syncthreads();
  int ob = m0 + wave * 16 + g * 4;
  int h = ob >> 5, d0 = ob & 31;
#pragma unroll
  for (int p = 0; p < 3; ++p) {
    const unsigned short* Wrow =
        wb + (size_t)p * 65536 + (size_t)(m0 + wave * 16 + cl) * 256 + g * 8;
    bf16x8 af[8];
#pragma unroll
    for (int ks = 0; ks < 8; ++ks) af[ks] = *(const bf16x8*)&Wrow[ks * 32];
    f32x4 acc[4] = {};
#pragma unroll
    for (int ks = 0; ks < 8; ++ks) {
#pragma unroll
      for (int nf = 0; nf < 4; ++nf) {
        bf16x8 bb = *(const bf16x8*)&Bs[nf * 16 + cl][ks * 32 + g * 8];
        acc[nf] = __builtin_amdgcn_mfma_f32_16x16x32_bf16(af[ks], bb, acc[nf], 0, 0, 0);
      }
    }
    const float* bias = (p == 0) ? bq : (p == 1) ? bk : bv;
    float sc = (p == 0) ? SM_C : 1.0f;
    float b0 = bias[ob] * sc, b1 = bias[ob + 1] * sc;
    float b2 = bias[ob + 2] * sc, b3 = bias[ob + 3] * sc;
#pragma unroll
    for (int nf = 0; nf < 4; ++nf) {
      int l = n0 + nf * 16 + cl;
      float v0 = acc[nf][0] + b0, v1 = acc[nf][1] + b1;
      float v2 = acc[nf][2] + b2, v3 = acc[nf][3] + b3;
      if (p < 2) {
        unsigned short* dst = ((p == 0) ? qt : kt) +
            ((size_t)(b * 8 + h) * Ll + l) * 32 + d0;
        *(uint2*)dst = make_uint2(packbf(v0, v1), packbf(v2, v3));
      } else {
        size_t base = (size_t)(b * 8 + h) * 32 + d0;
        vm[(base + 0) * Ll + l] = f2bfc(v0);
        vm[(base + 1) * Ll + l] = f2bfc(v1);
        vm[(base + 2) * Ll + l] = f2bfc(v2);
        vm[(base + 3) * Ll + l] = f2bfc(v3);
      }
    }
  }
}

// Flash attention, 32x32 swapped-QK^T, P in-register with sigma-permuted PV.
// 4 waves: (qsub = wave>>1) 32-q subtile, (sstr = wave&1) kl stream.
// LDS: K/V double-buffer (17.9 KB) with epilogue Osh/Ssh ALIASED onto it
// (barrier-protected) -> 3 blocks/CU if the scheduler LDS pool is 64 KB.
// bh-fastest grid pins 4 bh (1.2 MB K+V) per XCD L2.
__global__ __launch_bounds__(256) void k_attn(
    const unsigned short* __restrict__ qt,
    const unsigned short* __restrict__ kt,
    const unsigned short* __restrict__ vm,
    unsigned short* __restrict__ aot) {
  __shared__ __align__(16) char smem[17920];
  unsigned short (*Ks)[64][36] = (unsigned short (*)[64][36])smem;          // 9216B
  unsigned short (*Vs)[32][68] = (unsigned short (*)[32][68])(smem + 9216); // 8704B
  float (*Osh)[32][33] = (float (*)[32][33])smem;                           // 8448B
  float (*Ssh)[32] = (float (*)[32])(smem + 8448);                          // 256B

  int bh = blockIdx.x, b = bh >> 3, h = bh & 7;  // bh fastest: 4 bh per XCD
  int q0 = blockIdx.y * 64;
  int tid = threadIdx.x, wave = tid >> 6, lane = tid & 63;
  int qsub = wave >> 1, sstr = wave & 1;
  int hi = lane >> 5, c = lane & 31;

  const unsigned short* qb = qt + (size_t)bh * Ll * 32;
  const unsigned short* kb = kt + (size_t)bh * Ll * 32;
  const unsigned short* vb = vm + (size_t)bh * 32 * Ll;

  // Q as B-frag: qf[dh]: Q[q0+qsub*32+c][dh*16 + hi*8 + j]
  bf16x8 qf[2];
  qf[0] = *(const bf16x8*)&qb[(size_t)(q0 + qsub * 32 + c) * 32 + hi * 8];
  qf[1] = *(const bf16x8*)&qb[(size_t)(q0 + qsub * 32 + c) * 32 + 16 + hi * 8];

  bf16x8 ones;
#pragma unroll
  for (int i = 0; i < 8; ++i) ones[i] = (short)0x3F80;

  f32x16 oacc = {};
  f32x16 osum = {};

  int krow = tid >> 2, kcol = (tid & 3) * 8;  // K tile [64 kl][32 d]
  int vrow = tid >> 3, vcol = (tid & 7) * 8;  // V tile [32 d][64 kl]

  // prologue: stage tiles 0,1 (split uint2 writes: rows 8B-aligned)
  {
    uint4 k0 = *(const uint4*)&kb[(size_t)krow * 32 + kcol];
    uint4 k1 = *(const uint4*)&kb[(size_t)(64 + krow) * 32 + kcol];
    uint4 v0 = *(const uint4*)&vb[(size_t)vrow * Ll + vcol];
    uint4 v1 = *(const uint4*)&vb[(size_t)vrow * Ll + 64 + vcol];
    *(uint2*)&Ks[0][krow][kcol] = make_uint2(k0.x, k0.y);
    *(uint2*)&Ks[0][krow][kcol + 4] = make_uint2(k0.z, k0.w);
    *(uint2*)&Ks[1][krow][kcol] = make_uint2(k1.x, k1.y);
    *(uint2*)&Ks[1][krow][kcol + 4] = make_uint2(k1.z, k1.w);
    *(uint2*)&Vs[0][vrow][vcol] = make_uint2(v0.x, v0.y);
    *(uint2*)&Vs[0][vrow][vcol + 4] = make_uint2(v0.z, v0.w);
    *(uint2*)&Vs[1][vrow][vcol] = make_uint2(v1.x, v1.y);
    *(uint2*)&Vs[1][vrow][vcol + 4] = make_uint2(v1.z, v1.w);
  }

  uint4 kr0, kr1, vr0, vr1;
  for (int j = 0; j < 18; ++j) {
    __syncthreads();  // staged pair visible
    if (j < 17) {  // issue next-pair loads early (hide HBM/L2 latency)
      int ta = (2 * j + 2) * 64, tb = ta + 64;
      kr0 = *(const uint4*)&kb[(size_t)(ta + krow) * 32 + kcol];
      kr1 = *(const uint4*)&kb[(size_t)(tb + krow) * 32 + kcol];
      vr0 = *(const uint4*)&vb[(size_t)vrow * Ll + ta + vcol];
      vr1 = *(const uint4*)&vb[(size_t)vrow * Ll + tb + vcol];
    }
    // ---- S^T = K . Q^T over this wave's 64-kl tile (stream sstr) ----
    f32x16 p_[2];
#pragma unroll
    for (int fb = 0; fb < 2; ++fb) {
      f32x16 z = {};
#pragma unroll
      for (int dh = 0; dh < 2; ++dh) {
        union { bf16x8 v; uint2 u2[2]; } kf;
        kf.u2[0] = *(const uint2*)&Ks[sstr][fb * 32 + c][dh * 16 + hi * 8];
        kf.u2[1] = *(const uint2*)&Ks[sstr][fb * 32 + c][dh * 16 + hi * 8 + 4];
        z = __builtin_amdgcn_mfma_f32_32x32x16_bf16(kf.v, qf[dh], z, 0, 0, 0);
      }
      p_[fb] = z;
    }
    // softmax numerator: one exp2 per score
#pragma unroll
    for (int fb = 0; fb < 2; ++fb)
#pragma unroll
      for (int r = 0; r < 16; ++r) p_[fb][r] = EXP2(p_[fb][r]);
    // pack in natural register order (RNE); Wp.v8[ks] IS the PV A-frag (sigma)
    union { unsigned w[16]; bf16x8 v8[4]; } Wp;
#pragma unroll
    for (int m = 0; m < 16; ++m)
      Wp.w[m] = packbf(p_[m >> 3][2 * (m & 7)], p_[m >> 3][2 * (m & 7) + 1]);
    // PV + denominator: V read at sigma-permuted kl offsets (two b64s)
#pragma unroll
    for (int ks = 0; ks < 4; ++ks) {
      union { bf16x8 v; uint2 u2[2]; } vf;
      vf.u2[0] = *(const uint2*)&Vs[sstr][c][ks * 16 + hi * 4];
      vf.u2[1] = *(const uint2*)&Vs[sstr][c][ks * 16 + 8 + hi * 4];
      oacc = __builtin_amdgcn_mfma_f32_32x32x16_bf16(Wp.v8[ks], vf.v, oacc, 0, 0, 0);
      osum = __builtin_amdgcn_mfma_f32_32x32x16_bf16(Wp.v8[ks], ones, osum, 0, 0, 0);
    }
    __syncthreads();  // compute reads done
    if (j < 17) {     // write-late into the slots
      *(uint2*)&Ks[0][krow][kcol] = make_uint2(kr0.x, kr0.y);
      *(uint2*)&Ks[0][krow][kcol + 4] = make_uint2(kr0.z, kr0.w);
      *(uint2*)&Ks[1][krow][kcol] = make_uint2(kr1.x, kr1.y);
      *(uint2*)&Ks[1][krow][kcol + 4] = make_uint2(kr1.z, kr1.w);
      *(uint2*)&Vs[0][vrow][vcol] = make_uint2(vr0.x, vr0.y);
      *(uint2*)&Vs[0][vrow][vcol + 4] = make_uint2(vr0.z, vr0.w);
      *(uint2*)&Vs[1][vrow][vcol] = make_uint2(vr1.x, vr1.y);
      *(uint2*)&Vs[1][vrow][vcol + 4] = make_uint2(vr1.z, vr1.w);
    }
  }

  __syncthreads();  // all K/V reads complete before Osh/Ssh alias the buffers

  // combine the two kl-streams, normalize, store
  if (sstr == 1) {
#pragma unroll
    for (int r = 0; r < 16; ++r) {
      int qrl = (r & 3) + 8 * (r >> 2) + 4 * hi;
      Osh[qsub][qrl][c] = oacc[r];
      if (c == 0) Ssh[qsub][qrl] = osum[r];
    }
  }
  __syncthreads();
  if (sstr == 0) {
    unsigned short* ob = aot + ((size_t)b * Ll + q0 + qsub * 32) * 256 + h * 32 + c;
#pragma unroll
    for (int r = 0; r < 16; ++r) {
      int qrl = (r & 3) + 8 * (r >> 2) + 4 * hi;
      float ot = oacc[r] + Osh[qsub][qrl][c];
      float st = osum[r] + Ssh[qsub][qrl];
      ob[(size_t)qrl * 256] = f2bfc(ot * RCP(st));
    }
  }
}

// Final projection: out[b][o][l] fp32 = wo . AOT + bo
__global__ __launch_bounds__(256) void k_oproj(
    const unsigned short* __restrict__ aot, const unsigned short* __restrict__ wb,
    const float* __restrict__ bo, float* __restrict__ out) {
  __shared__ __align__(16) unsigned short Bs[64][264];
  int b = blockIdx.z;
  int m0 = blockIdx.y * 64, n0 = blockIdx.x * 64;
  int tid = threadIdx.x, lane = tid & 63, wave = tid >> 6;
  int g = lane >> 4, cl = lane & 15;
  const uint4* bp = (const uint4*)(aot + ((size_t)b * Ll + n0) * 256);
#pragma unroll
  for (int j = 0; j < 8; ++j) {
    int idx = j * 256 + tid;
    *(uint4*)&Bs[idx >> 5][(idx & 31) * 8] = bp[idx];
  }
  __syncthreads();
  const unsigned short* Wrow =
      wb + (size_t)3 * 65536 + (size_t)(m0 + wave * 16 + cl) * 256 + g * 8;
  bf16x8 af[8];
#pragma unroll
  for (int ks = 0; ks < 8; ++ks) af[ks] = *(const bf16x8*)&Wrow[ks * 32];
  f32x4 acc[4] = {};
#pragma unroll
  for (int ks = 0; ks < 8; ++ks) {
#pragma unroll
    for (int nf = 0; nf < 4; ++nf) {
      bf16x8 bb = *(const bf16x8*)&Bs[nf * 16 + cl][ks * 32 + g * 8];
      acc[nf] = __builtin_amdgcn_mfma_f32_16x16x32_bf16(af[ks], bb, acc[nf], 0, 0, 0);
    }
  }
  int ob = m0 + wave * 16 + g * 4;
  float b0 = bo[ob], b1 = bo[ob + 1], b2 = bo[ob + 2], b3 = bo[ob + 3];
#pragma unroll
  for (int nf = 0; nf < 4; ++nf) {
    int l = n0 + nf * 16 + cl;
    float* dst = out + ((size_t)b * 256 + ob) * Ll + l;
    dst[(size_t)0 * Ll] = acc[nf][0] + b0;
    dst[(size_t)1 * Ll] = acc[nf][1] + b1;
    dst[(size_t)2 * Ll] = acc[nf][2] + b2;
    dst[(size_t)3 * Ll] = acc[nf][3] + b3;
  }
}

extern "C" void kernel_launch(void* const* d_in, const int* in_sizes, int n_in,
                              void* d_out, int out_size, void* d_ws, size_t ws_size,
                              hipStream_t stream) {
  (void)in_sizes; (void)n_in; (void)out_size; (void)ws_size;
  const float* x  = (const float*)d_in[0];
  const float* wq = (const float*)d_in[1];
  const float* bq = (const float*)d_in[2];
  const float* wk = (const float*)d_in[3];
  const float* bk = (const float*)d_in[4];
  const float* wv = (const float*)d_in[5];
  const float* bv = (const float*)d_in[6];
  const float* wo = (const float*)d_in[7];
  const float* bo = (const float*)d_in[8];
  float* out = (float*)d_out;

  const size_t CH = (size_t)4 * Ll * Cc;  // elements per bf16 chunk
  unsigned short* xt = (unsigned short*)d_ws;
  unsigned short* qt = xt + CH;
  unsigned short* kt = xt + 2 * CH;
  unsigned short* vm = xt + 3 * CH;
  unsigned short* wbq = xt + 4 * CH;  // [4][256][256] bf16 weights
  unsigned short* aot = xt;           // reuse XT slot after projections

  k_prep<<<dim3(416), 256, 0, stream>>>(x, wq, wk, wv, wo, wbq, xt);
  k_qkv<<<dim3(36, 4, 4), 256, 0, stream>>>(xt, wbq, bq, bk, bv, qt, kt, vm);
  k_attn<<<dim3(32, 36), 256, 0, stream>>>(qt, kt, vm, aot);
  k_oproj<<<dim3(36, 4, 4), 256, 0, stream>>>(aot, wbq, bo, out);
}